// Round 1
// baseline (269.150 us; speedup 1.0000x reference)
//
#include <hip/hip_runtime.h>

#define NSRC 100000
#define NDST 10000
#define NEDGE 320000
#define FIN 128
#define HID 256
#define NCLS 3
#define NEG_SLOPE 0.2f

// ---------- wa = W @ att  (128-vector), both att_src and att_dst ----------
__global__ void watt_kernel(const float* __restrict__ W, const float* __restrict__ att_src,
                            const float* __restrict__ att_dst,
                            float* __restrict__ wa_src, float* __restrict__ wa_dst) {
  int k = threadIdx.x;  // 0..127
  float s1 = 0.f, s2 = 0.f;
  for (int h = 0; h < HID; ++h) {
    float w = W[k * HID + h];
    s1 += w * att_src[h];
    s2 += w * att_dst[h];
  }
  wa_src[k] = s1;
  wa_dst[k] = s2;
}

// ---------- a[row] = X[row,:] . wa   (one wave per row, float2 loads) ----------
__global__ void matvec_kernel(const float* __restrict__ X, const float* __restrict__ wa,
                              float* __restrict__ a, int nrows) {
  int gid = blockIdx.x * blockDim.x + threadIdx.x;
  int row = gid >> 6;
  int lane = threadIdx.x & 63;
  if (row >= nrows) return;
  float2 v = ((const float2*)(X + (size_t)row * FIN))[lane];
  float p = v.x * wa[2 * lane] + v.y * wa[2 * lane + 1];
#pragma unroll
  for (int off = 32; off; off >>= 1) p += __shfl_down(p, off);
  if (lane == 0) a[row] = p;
}

// ---------- histogram of edge_dst ----------
__global__ void hist_kernel(const int* __restrict__ edge_dst, int* __restrict__ counts, int E) {
  int e = blockIdx.x * blockDim.x + threadIdx.x;
  if (e >= E) return;
  atomicAdd(&counts[edge_dst[e]], 1);
}

// ---------- exclusive scan of counts[n] -> offsets[n+1] (single block) ----------
__global__ void scan_kernel(const int* __restrict__ counts, int* __restrict__ offsets, int n) {
  __shared__ int partial[1024];
  int tid = threadIdx.x;
  int per = (n + 1023) / 1024;
  int begin = tid * per;
  int endi = min(begin + per, n);
  int sum = 0;
  for (int i = begin; i < endi; ++i) sum += counts[i];
  partial[tid] = sum;
  __syncthreads();
  for (int off = 1; off < 1024; off <<= 1) {
    int v = (tid >= off) ? partial[tid - off] : 0;
    __syncthreads();
    partial[tid] += v;
    __syncthreads();
  }
  int run = (tid > 0) ? partial[tid - 1] : 0;
  for (int i = begin; i < endi; ++i) { offsets[i] = run; run += counts[i]; }
  if (tid == 1023) offsets[n] = partial[1023];
}

// ---------- compute logits, scatter edges into dst-sorted order ----------
__global__ void scatter_kernel(const int* __restrict__ edge_src, const int* __restrict__ edge_dst,
                               const float* __restrict__ a_src, const float* __restrict__ a_dst,
                               const int* __restrict__ offsets, int* __restrict__ cursor,
                               int* __restrict__ s_src, float* __restrict__ s_logit, int E) {
  int e = blockIdx.x * blockDim.x + threadIdx.x;
  if (e >= E) return;
  int s = edge_src[e], d = edge_dst[e];
  float z = a_dst[d] + a_src[s];
  float logit = (z >= 0.f) ? z : NEG_SLOPE * z;
  int pos = offsets[d] + atomicAdd(&cursor[d], 1);
  s_src[pos] = s;
  s_logit[pos] = logit;
}

// ---------- per-dst softmax-weighted aggregation in x-space (128 feats) ----------
__global__ void agg_kernel(const int* __restrict__ offsets, const int* __restrict__ s_src,
                           const float* __restrict__ s_logit, const float* __restrict__ x_src,
                           float* __restrict__ aggN) {
  int d = blockIdx.x;
  int t = threadIdx.x;  // 0..127
  int start = offsets[d], end = offsets[d + 1];
  __shared__ float red[128];
  float m = -3.402823466e38f;
  for (int e = start + t; e < end; e += 128) m = fmaxf(m, s_logit[e]);
  red[t] = m;
  __syncthreads();
#pragma unroll
  for (int off = 64; off; off >>= 1) {
    if (t < off) red[t] = fmaxf(red[t], red[t + off]);
    __syncthreads();
  }
  m = red[0];
  float acc = 0.f, denom = 0.f;
  for (int e = start; e < end; ++e) {
    float w = expf(s_logit[e] - m);   // broadcast loads; w identical in all lanes
    denom += w;
    acc += w * x_src[(size_t)s_src[e] * FIN + t];
  }
  aggN[d * FIN + t] = acc / (denom + 1e-16f);
}

// ---------- out = aggN @ W + bias, then scores = out @ Wc + bc, log_softmax ----------
__global__ void out_kernel(const float* __restrict__ aggN, const float* __restrict__ W,
                           const float* __restrict__ bias, const float* __restrict__ Wc,
                           const float* __restrict__ bc, float* __restrict__ out, int ndst) {
  __shared__ float sA[32 * 128];
  __shared__ float sO[32 * 257];  // padded stride to dodge bank conflicts
  int t = threadIdx.x;  // 0..255
  int r0 = blockIdx.x * 32;
  for (int i = t; i < 32 * 128; i += 256) {
    int r = i >> 7, k = i & 127;
    int row = r0 + r;
    sA[i] = (row < ndst) ? aggN[(size_t)row * FIN + k] : 0.f;
  }
  __syncthreads();
  float acc[32];
#pragma unroll
  for (int r = 0; r < 32; ++r) acc[r] = 0.f;
  for (int k = 0; k < 128; ++k) {
    float w = W[k * HID + t];
#pragma unroll
    for (int r = 0; r < 32; ++r) acc[r] += sA[r * 128 + k] * w;
  }
  float b = bias[t];
#pragma unroll
  for (int r = 0; r < 32; ++r) sO[r * 257 + t] = acc[r] + b;
  __syncthreads();
  if (t < 32) {
    int row = r0 + t;
    if (row < ndst) {
      float s0 = bc[0], s1 = bc[1], s2 = bc[2];
      for (int h = 0; h < HID; ++h) {
        float v = sO[t * 257 + h];
        s0 += v * Wc[h * NCLS + 0];
        s1 += v * Wc[h * NCLS + 1];
        s2 += v * Wc[h * NCLS + 2];
      }
      float mx = fmaxf(s0, fmaxf(s1, s2));
      float l = logf(expf(s0 - mx) + expf(s1 - mx) + expf(s2 - mx));
      out[row * NCLS + 0] = s0 - mx - l;
      out[row * NCLS + 1] = s1 - mx - l;
      out[row * NCLS + 2] = s2 - mx - l;
    }
  }
}

extern "C" void kernel_launch(void* const* d_in, const int* in_sizes, int n_in,
                              void* d_out, int out_size, void* d_ws, size_t ws_size,
                              hipStream_t stream) {
  const float* x_src   = (const float*)d_in[0];
  const float* x_dst   = (const float*)d_in[1];
  const int*   edge_src = (const int*)d_in[2];
  const int*   edge_dst = (const int*)d_in[3];
  const float* W       = (const float*)d_in[4];
  const float* att_src = (const float*)d_in[5];
  const float* att_dst = (const float*)d_in[6];
  const float* bias    = (const float*)d_in[7];
  const float* Wc      = (const float*)d_in[8];
  const float* bc      = (const float*)d_in[9];
  float* out = (float*)d_out;

  // ---- workspace carve (256B aligned chunks) ----
  char* p = (char*)d_ws;
  auto carve = [&](size_t bytes) {
    void* r = (void*)p;
    p += (bytes + 255) & ~(size_t)255;
    return r;
  };
  float* wa_src   = (float*)carve(FIN * 4);
  float* wa_dst   = (float*)carve(FIN * 4);
  float* a_src    = (float*)carve((size_t)NSRC * 4);
  float* a_dst    = (float*)carve((size_t)NDST * 4);
  int*   counts   = (int*)carve((size_t)NDST * 4);
  int*   cursor   = (int*)carve((size_t)NDST * 4);
  int*   offsets  = (int*)carve((size_t)(NDST + 1) * 4);
  int*   s_src    = (int*)carve((size_t)NEDGE * 4);
  float* s_logit  = (float*)carve((size_t)NEDGE * 4);
  float* aggN     = (float*)carve((size_t)NDST * FIN * 4);

  // zero counts + cursor (adjacent carves → contiguous region of 2*padded size)
  hipMemsetAsync(counts, 0, ((size_t)NDST * 4 + 255 & ~(size_t)255) * 2, stream);

  watt_kernel<<<1, 128, 0, stream>>>(W, att_src, att_dst, wa_src, wa_dst);
  {
    int waves = NSRC;  // one wave per row
    int blocks = (waves * 64 + 255) / 256;
    matvec_kernel<<<blocks, 256, 0, stream>>>(x_src, wa_src, a_src, NSRC);
  }
  {
    int blocks = (NDST * 64 + 255) / 256;
    matvec_kernel<<<blocks, 256, 0, stream>>>(x_dst, wa_dst, a_dst, NDST);
  }
  hist_kernel<<<(NEDGE + 255) / 256, 256, 0, stream>>>(edge_dst, counts, NEDGE);
  scan_kernel<<<1, 1024, 0, stream>>>(counts, offsets, NDST);
  scatter_kernel<<<(NEDGE + 255) / 256, 256, 0, stream>>>(edge_src, edge_dst, a_src, a_dst,
                                                          offsets, cursor, s_src, s_logit, NEDGE);
  agg_kernel<<<NDST, 128, 0, stream>>>(offsets, s_src, s_logit, x_src, aggN);
  out_kernel<<<(NDST + 31) / 32, 256, 0, stream>>>(aggN, W, bias, Wc, bc, out, NDST);
}

// Round 2
// 215.381 us; speedup vs baseline: 1.2496x; 1.2496x over previous
//
#include <hip/hip_runtime.h>
#include <float.h>

#define NSRC 100000
#define NDST 10000
#define NEDGE 320000
#define FIN 128
#define HID 256
#define NCLS 3
#define NEG_SLOPE 0.2f

// ---------- prep: wa = W@att (both), Wf = W@Wc [128x3], bf = bias@Wc + bc ----------
__global__ void prep_kernel(const float* __restrict__ W, const float* __restrict__ att_src,
                            const float* __restrict__ att_dst, const float* __restrict__ bias,
                            const float* __restrict__ Wc, const float* __restrict__ bc,
                            float* __restrict__ wa_src, float* __restrict__ wa_dst,
                            float* __restrict__ Wf, float* __restrict__ bf) {
  int k = threadIdx.x;  // 0..127
  float s1 = 0.f, s2 = 0.f, f0 = 0.f, f1 = 0.f, f2 = 0.f;
  for (int h = 0; h < HID; ++h) {
    float w = W[k * HID + h];
    s1 += w * att_src[h];
    s2 += w * att_dst[h];
    f0 += w * Wc[h * NCLS + 0];
    f1 += w * Wc[h * NCLS + 1];
    f2 += w * Wc[h * NCLS + 2];
  }
  wa_src[k] = s1;
  wa_dst[k] = s2;
  Wf[k * NCLS + 0] = f0;
  Wf[k * NCLS + 1] = f1;
  Wf[k * NCLS + 2] = f2;
  if (k < NCLS) {
    float b = bc[k];
    for (int h = 0; h < HID; ++h) b += bias[h] * Wc[h * NCLS + k];
    bf[k] = b;
  }
}

// ---------- a[row] = X[row,:] . wa  (half-wave per row, float4 loads) ----------
__global__ void matvec_kernel(const float* __restrict__ X, const float* __restrict__ wa,
                              float* __restrict__ a, int nrows) {
  int gid = blockIdx.x * blockDim.x + threadIdx.x;
  int row = gid >> 5;           // half-wave (32 lanes) per row
  int l = threadIdx.x & 31;
  if (row >= nrows) return;
  float4 v = ((const float4*)(X + (size_t)row * FIN))[l];
  float4 w = ((const float4*)wa)[l];
  float p = v.x * w.x + v.y * w.y + v.z * w.z + v.w * w.w;
#pragma unroll
  for (int off = 16; off; off >>= 1) p += __shfl_down(p, off);
  if (l == 0) a[row] = p;
}

// ---------- histogram of edge_dst ----------
__global__ void hist_kernel(const int* __restrict__ edge_dst, int* __restrict__ counts, int E) {
  int e = blockIdx.x * blockDim.x + threadIdx.x;
  if (e >= E) return;
  atomicAdd(&counts[edge_dst[e]], 1);
}

// ---------- exclusive scan of counts[n] -> offsets[n+1] (single block) ----------
__global__ void scan_kernel(const int* __restrict__ counts, int* __restrict__ offsets, int n) {
  __shared__ int partial[1024];
  int tid = threadIdx.x;
  int per = (n + 1023) / 1024;
  int begin = tid * per;
  int endi = min(begin + per, n);
  int sum = 0;
  for (int i = begin; i < endi; ++i) sum += counts[i];
  partial[tid] = sum;
  __syncthreads();
  for (int off = 1; off < 1024; off <<= 1) {
    int v = (tid >= off) ? partial[tid - off] : 0;
    __syncthreads();
    partial[tid] += v;
    __syncthreads();
  }
  int run = (tid > 0) ? partial[tid - 1] : 0;
  for (int i = begin; i < endi; ++i) { offsets[i] = run; run += counts[i]; }
  if (tid == 1023) offsets[n] = partial[1023];
}

// ---------- compute logits, scatter edges into dst-sorted order ----------
__global__ void scatter_kernel(const int* __restrict__ edge_src, const int* __restrict__ edge_dst,
                               const float* __restrict__ a_src, const float* __restrict__ a_dst,
                               const int* __restrict__ offsets, int* __restrict__ cursor,
                               int* __restrict__ s_src, float* __restrict__ s_logit, int E) {
  int e = blockIdx.x * blockDim.x + threadIdx.x;
  if (e >= E) return;
  int s = edge_src[e], d = edge_dst[e];
  float z = a_dst[d] + a_src[s];
  float logit = (z >= 0.f) ? z : NEG_SLOPE * z;
  int pos = offsets[d] + atomicAdd(&cursor[d], 1);
  s_src[pos] = s;
  s_logit[pos] = logit;
}

// ---------- one wave per dst: softmax-weighted x-space aggregation + fused classifier ----------
__global__ void agg_out_kernel(const int* __restrict__ offsets, const int* __restrict__ s_src,
                               const float* __restrict__ s_logit, const float* __restrict__ x_src,
                               const float* __restrict__ Wf, const float* __restrict__ bf,
                               float* __restrict__ out, int ndst) {
  int wave = threadIdx.x >> 6;
  int lane = threadIdx.x & 63;
  int d = blockIdx.x * 4 + wave;
  if (d >= ndst) return;
  int start = offsets[d], end = offsets[d + 1];

  // phase 1: segment max (coalesced strided reads + wave reduce)
  float m = -FLT_MAX;
  for (int e = start + lane; e < end; e += 64) m = fmaxf(m, s_logit[e]);
#pragma unroll
  for (int off = 32; off; off >>= 1) m = fmaxf(m, __shfl_down(m, off));
  m = __shfl(m, 0);

  // phase 2: weighted aggregate of x_src rows (lane holds feats 2*lane, 2*lane+1)
  float accx = 0.f, accy = 0.f, dsum = 0.f;
  for (int base = start; base < end; base += 64) {
    int cnt = min(64, end - base);
    float w = 0.f;
    int s = 0;
    if (lane < cnt) {
      s = s_src[base + lane];
      w = __expf(s_logit[base + lane] - m);
    }
    dsum += w;
    for (int i = 0; i < cnt; ++i) {
      float wi = __shfl(w, i);
      int si = __shfl(s, i);
      float2 v = ((const float2*)(x_src + (size_t)si * FIN))[lane];
      accx += wi * v.x;
      accy += wi * v.y;
    }
  }
#pragma unroll
  for (int off = 32; off; off >>= 1) dsum += __shfl_down(dsum, off);
  dsum = __shfl(dsum, 0) + 1e-16f;

  // fused classifier: scores_c = (acc . Wf[:,c]) / dsum + bf_c, then log_softmax
  int k = 2 * lane;
  float p0 = accx * Wf[k * NCLS + 0] + accy * Wf[(k + 1) * NCLS + 0];
  float p1 = accx * Wf[k * NCLS + 1] + accy * Wf[(k + 1) * NCLS + 1];
  float p2 = accx * Wf[k * NCLS + 2] + accy * Wf[(k + 1) * NCLS + 2];
#pragma unroll
  for (int off = 32; off; off >>= 1) {
    p0 += __shfl_down(p0, off);
    p1 += __shfl_down(p1, off);
    p2 += __shfl_down(p2, off);
  }
  if (lane == 0) {
    float s0 = p0 / dsum + bf[0];
    float s1 = p1 / dsum + bf[1];
    float s2 = p2 / dsum + bf[2];
    float mx = fmaxf(s0, fmaxf(s1, s2));
    float l = logf(__expf(s0 - mx) + __expf(s1 - mx) + __expf(s2 - mx));
    out[d * NCLS + 0] = s0 - mx - l;
    out[d * NCLS + 1] = s1 - mx - l;
    out[d * NCLS + 2] = s2 - mx - l;
  }
}

extern "C" void kernel_launch(void* const* d_in, const int* in_sizes, int n_in,
                              void* d_out, int out_size, void* d_ws, size_t ws_size,
                              hipStream_t stream) {
  const float* x_src    = (const float*)d_in[0];
  const float* x_dst    = (const float*)d_in[1];
  const int*   edge_src = (const int*)d_in[2];
  const int*   edge_dst = (const int*)d_in[3];
  const float* W        = (const float*)d_in[4];
  const float* att_src  = (const float*)d_in[5];
  const float* att_dst  = (const float*)d_in[6];
  const float* bias     = (const float*)d_in[7];
  const float* Wc       = (const float*)d_in[8];
  const float* bc       = (const float*)d_in[9];
  float* out = (float*)d_out;

  // ---- workspace carve (256B aligned chunks) ----
  char* p = (char*)d_ws;
  auto carve = [&](size_t bytes) {
    void* r = (void*)p;
    p += (bytes + 255) & ~(size_t)255;
    return r;
  };
  float* wa_src  = (float*)carve(FIN * 4);
  float* wa_dst  = (float*)carve(FIN * 4);
  float* Wf      = (float*)carve(FIN * NCLS * 4);
  float* bf      = (float*)carve(NCLS * 4);
  float* a_src   = (float*)carve((size_t)NSRC * 4);
  float* a_dst   = (float*)carve((size_t)NDST * 4);
  int*   counts  = (int*)carve((size_t)NDST * 4);
  int*   cursor  = (int*)carve((size_t)NDST * 4);
  int*   offsets = (int*)carve((size_t)(NDST + 1) * 4);
  int*   s_src   = (int*)carve((size_t)NEDGE * 4);
  float* s_logit = (float*)carve((size_t)NEDGE * 4);

  // zero counts + cursor (adjacent carves -> contiguous padded region x2)
  hipMemsetAsync(counts, 0, (((size_t)NDST * 4 + 255) & ~(size_t)255) * 2, stream);

  prep_kernel<<<1, 128, 0, stream>>>(W, att_src, att_dst, bias, Wc, bc, wa_src, wa_dst, Wf, bf);
  matvec_kernel<<<(NSRC * 32 + 255) / 256, 256, 0, stream>>>(x_src, wa_src, a_src, NSRC);
  matvec_kernel<<<(NDST * 32 + 255) / 256, 256, 0, stream>>>(x_dst, wa_dst, a_dst, NDST);
  hist_kernel<<<(NEDGE + 255) / 256, 256, 0, stream>>>(edge_dst, counts, NEDGE);
  scan_kernel<<<1, 1024, 0, stream>>>(counts, offsets, NDST);
  scatter_kernel<<<(NEDGE + 255) / 256, 256, 0, stream>>>(edge_src, edge_dst, a_src, a_dst,
                                                          offsets, cursor, s_src, s_logit, NEDGE);
  agg_out_kernel<<<(NDST + 3) / 4, 256, 0, stream>>>(offsets, s_src, s_logit, x_src, Wf, bf, out, NDST);
}

// Round 3
// 191.163 us; speedup vs baseline: 1.4080x; 1.1267x over previous
//
#include <hip/hip_runtime.h>
#include <float.h>

#define NSRC 100000
#define NDST 10000
#define NEDGE 320000
#define FIN 128
#define HID 256
#define NCLS 3
#define NEG_SLOPE 0.2f

// ---------- prep: wa = W@att (both), wfc[c][k] = (W@Wc)[k,c] (transposed cols), bf = bias@Wc + bc ----------
__global__ void prep_kernel(const float* __restrict__ W, const float* __restrict__ att_src,
                            const float* __restrict__ att_dst, const float* __restrict__ bias,
                            const float* __restrict__ Wc, const float* __restrict__ bc,
                            float* __restrict__ wa_src, float* __restrict__ wa_dst,
                            float* __restrict__ wfc, float* __restrict__ bf) {
  int k = threadIdx.x;  // 0..127
  float s1 = 0.f, s2 = 0.f, f0 = 0.f, f1 = 0.f, f2 = 0.f;
  for (int h = 0; h < HID; ++h) {
    float w = W[k * HID + h];
    s1 += w * att_src[h];
    s2 += w * att_dst[h];
    f0 += w * Wc[h * NCLS + 0];
    f1 += w * Wc[h * NCLS + 1];
    f2 += w * Wc[h * NCLS + 2];
  }
  wa_src[k] = s1;
  wa_dst[k] = s2;
  wfc[0 * FIN + k] = f0;
  wfc[1 * FIN + k] = f1;
  wfc[2 * FIN + k] = f2;
  if (k < NCLS) {
    float b = bc[k];
    for (int h = 0; h < HID; ++h) b += bias[h] * Wc[h * NCLS + k];
    bf[k] = b;
  }
}

// ---------- x_src pass: a[row] = x.wa_src AND q4[row] = (x.Wf0, x.Wf1, x.Wf2, 0) ----------
__global__ void matvec_src_kernel(const float* __restrict__ X, const float* __restrict__ wa,
                                  const float* __restrict__ wfc, float* __restrict__ a,
                                  float4* __restrict__ q4, int nrows) {
  int gid = blockIdx.x * blockDim.x + threadIdx.x;
  int row = gid >> 5;  // half-wave (32 lanes) per row
  int l = threadIdx.x & 31;
  if (row >= nrows) return;
  float4 v = ((const float4*)(X + (size_t)row * FIN))[l];
  float4 w = ((const float4*)wa)[l];
  float4 c0 = ((const float4*)(wfc + 0 * FIN))[l];
  float4 c1 = ((const float4*)(wfc + 1 * FIN))[l];
  float4 c2 = ((const float4*)(wfc + 2 * FIN))[l];
  float p0 = v.x * w.x + v.y * w.y + v.z * w.z + v.w * w.w;
  float p1 = v.x * c0.x + v.y * c0.y + v.z * c0.z + v.w * c0.w;
  float p2 = v.x * c1.x + v.y * c1.y + v.z * c1.z + v.w * c1.w;
  float p3 = v.x * c2.x + v.y * c2.y + v.z * c2.z + v.w * c2.w;
#pragma unroll
  for (int off = 16; off; off >>= 1) {
    p0 += __shfl_down(p0, off);
    p1 += __shfl_down(p1, off);
    p2 += __shfl_down(p2, off);
    p3 += __shfl_down(p3, off);
  }
  if (l == 0) {
    a[row] = p0;
    q4[row] = make_float4(p1, p2, p3, 0.f);
  }
}

// ---------- x_dst pass: a[row] = x.wa_dst ----------
__global__ void matvec_kernel(const float* __restrict__ X, const float* __restrict__ wa,
                              float* __restrict__ a, int nrows) {
  int gid = blockIdx.x * blockDim.x + threadIdx.x;
  int row = gid >> 5;
  int l = threadIdx.x & 31;
  if (row >= nrows) return;
  float4 v = ((const float4*)(X + (size_t)row * FIN))[l];
  float4 w = ((const float4*)wa)[l];
  float p = v.x * w.x + v.y * w.y + v.z * w.z + v.w * w.w;
#pragma unroll
  for (int off = 16; off; off >>= 1) p += __shfl_down(p, off);
  if (l == 0) a[row] = p;
}

// ---------- histogram of edge_dst ----------
__global__ void hist_kernel(const int* __restrict__ edge_dst, int* __restrict__ counts, int E) {
  int e = blockIdx.x * blockDim.x + threadIdx.x;
  if (e >= E) return;
  atomicAdd(&counts[edge_dst[e]], 1);
}

// ---------- exclusive scan of counts[n] -> offsets[n+1] (single block) ----------
__global__ void scan_kernel(const int* __restrict__ counts, int* __restrict__ offsets, int n) {
  __shared__ int partial[1024];
  int tid = threadIdx.x;
  int per = (n + 1023) / 1024;
  int begin = tid * per;
  int endi = min(begin + per, n);
  int sum = 0;
  for (int i = begin; i < endi; ++i) sum += counts[i];
  partial[tid] = sum;
  __syncthreads();
  for (int off = 1; off < 1024; off <<= 1) {
    int v = (tid >= off) ? partial[tid - off] : 0;
    __syncthreads();
    partial[tid] += v;
    __syncthreads();
  }
  int run = (tid > 0) ? partial[tid - 1] : 0;
  for (int i = begin; i < endi; ++i) { offsets[i] = run; run += counts[i]; }
  if (tid == 1023) offsets[n] = partial[1023];
}

// ---------- compute logits, scatter edges into dst-sorted order ----------
__global__ void scatter_kernel(const int* __restrict__ edge_src, const int* __restrict__ edge_dst,
                               const float* __restrict__ a_src, const float* __restrict__ a_dst,
                               const int* __restrict__ offsets, int* __restrict__ cursor,
                               int* __restrict__ s_src, float* __restrict__ s_logit, int E) {
  int e = blockIdx.x * blockDim.x + threadIdx.x;
  if (e >= E) return;
  int s = edge_src[e], d = edge_dst[e];
  float z = a_dst[d] + a_src[s];
  float logit = (z >= 0.f) ? z : NEG_SLOPE * z;
  int pos = offsets[d] + atomicAdd(&cursor[d], 1);
  s_src[pos] = s;
  s_logit[pos] = logit;
}

// ---------- one wave per dst: softmax over segment, q-space accumulate, log_softmax out ----------
__global__ void agg_out_kernel(const int* __restrict__ offsets, const int* __restrict__ s_src,
                               const float* __restrict__ s_logit, const float4* __restrict__ q4,
                               const float* __restrict__ bf, float* __restrict__ out, int ndst) {
  int wave = threadIdx.x >> 6;
  int lane = threadIdx.x & 63;
  int d = blockIdx.x * 4 + wave;
  if (d >= ndst) return;
  int start = offsets[d], end = offsets[d + 1];

  // segment max
  float m = -FLT_MAX;
  for (int e = start + lane; e < end; e += 64) m = fmaxf(m, s_logit[e]);
#pragma unroll
  for (int off = 32; off; off >>= 1) m = fmaxf(m, __shfl_down(m, off));
  m = __shfl(m, 0);

  // weighted accumulate in q-space (3 floats per edge)
  float dsum = 0.f, a0 = 0.f, a1 = 0.f, a2 = 0.f;
  for (int e = start + lane; e < end; e += 64) {
    float w = __expf(s_logit[e] - m);
    float4 qv = q4[s_src[e]];
    dsum += w;
    a0 += w * qv.x;
    a1 += w * qv.y;
    a2 += w * qv.z;
  }
#pragma unroll
  for (int off = 32; off; off >>= 1) {
    dsum += __shfl_down(dsum, off);
    a0 += __shfl_down(a0, off);
    a1 += __shfl_down(a1, off);
    a2 += __shfl_down(a2, off);
  }
  if (lane == 0) {
    dsum += 1e-16f;
    float s0 = a0 / dsum + bf[0];
    float s1 = a1 / dsum + bf[1];
    float s2 = a2 / dsum + bf[2];
    float mx = fmaxf(s0, fmaxf(s1, s2));
    float l = logf(__expf(s0 - mx) + __expf(s1 - mx) + __expf(s2 - mx));
    out[d * NCLS + 0] = s0 - mx - l;
    out[d * NCLS + 1] = s1 - mx - l;
    out[d * NCLS + 2] = s2 - mx - l;
  }
}

extern "C" void kernel_launch(void* const* d_in, const int* in_sizes, int n_in,
                              void* d_out, int out_size, void* d_ws, size_t ws_size,
                              hipStream_t stream) {
  const float* x_src    = (const float*)d_in[0];
  const float* x_dst    = (const float*)d_in[1];
  const int*   edge_src = (const int*)d_in[2];
  const int*   edge_dst = (const int*)d_in[3];
  const float* W        = (const float*)d_in[4];
  const float* att_src  = (const float*)d_in[5];
  const float* att_dst  = (const float*)d_in[6];
  const float* bias     = (const float*)d_in[7];
  const float* Wc       = (const float*)d_in[8];
  const float* bc       = (const float*)d_in[9];
  float* out = (float*)d_out;

  // ---- workspace carve (256B aligned chunks) ----
  char* p = (char*)d_ws;
  auto carve = [&](size_t bytes) {
    void* r = (void*)p;
    p += (bytes + 255) & ~(size_t)255;
    return r;
  };
  float*  wa_src  = (float*)carve(FIN * 4);
  float*  wa_dst  = (float*)carve(FIN * 4);
  float*  wfc     = (float*)carve(NCLS * FIN * 4);
  float*  bf      = (float*)carve(NCLS * 4);
  float*  a_src   = (float*)carve((size_t)NSRC * 4);
  float*  a_dst   = (float*)carve((size_t)NDST * 4);
  float4* q4      = (float4*)carve((size_t)NSRC * 16);
  int*    counts  = (int*)carve((size_t)NDST * 4);
  int*    cursor  = (int*)carve((size_t)NDST * 4);
  int*    offsets = (int*)carve((size_t)(NDST + 1) * 4);
  int*    s_src   = (int*)carve((size_t)NEDGE * 4);
  float*  s_logit = (float*)carve((size_t)NEDGE * 4);

  // zero counts + cursor (adjacent carves -> contiguous padded region x2)
  hipMemsetAsync(counts, 0, (((size_t)NDST * 4 + 255) & ~(size_t)255) * 2, stream);

  prep_kernel<<<1, 128, 0, stream>>>(W, att_src, att_dst, bias, Wc, bc, wa_src, wa_dst, wfc, bf);
  matvec_src_kernel<<<(NSRC * 32 + 255) / 256, 256, 0, stream>>>(x_src, wa_src, wfc, a_src, q4, NSRC);
  matvec_kernel<<<(NDST * 32 + 255) / 256, 256, 0, stream>>>(x_dst, wa_dst, a_dst, NDST);
  hist_kernel<<<(NEDGE + 255) / 256, 256, 0, stream>>>(edge_dst, counts, NEDGE);
  scan_kernel<<<1, 1024, 0, stream>>>(counts, offsets, NDST);
  scatter_kernel<<<(NEDGE + 255) / 256, 256, 0, stream>>>(edge_src, edge_dst, a_src, a_dst,
                                                          offsets, cursor, s_src, s_logit, NEDGE);
  agg_out_kernel<<<(NDST + 3) / 4, 256, 0, stream>>>(offsets, s_src, s_logit, q4, bf, out, NDST);
}